// Round 1
// baseline (51.497 us; speedup 1.0000x reference)
//
#include <hip/hip_runtime.h>

// Problem constants (reference: B=128, S=2048, D=128)
#define BB 128
#define SS 2048
#define DD 128

// ---------------------------------------------------------------------------
// Kernel 1: build the position-encoding table pe[S][D] in f32.
// angle[s][j] = (s+1) / 10000^(2*(j/2)/D); row s==0 stays raw (reference quirk),
// rows s>=1: even j -> sin(angle), odd j -> cos(angle).
// ---------------------------------------------------------------------------
__global__ __launch_bounds__(256) void pe_init_kernel(float* __restrict__ pe) {
    int idx = blockIdx.x * 256 + threadIdx.x;
    if (idx >= SS * DD) return;
    int s = idx >> 7;          // row (D=128)
    int j = idx & (DD - 1);    // col
    float expo = -(float)(2 * (j >> 1)) / (float)DD;
    float invf = powf(10000.0f, expo);
    float angle = (float)(s + 1) * invf;
    float v;
    if (s == 0) {
        v = angle;                                    // row 0 stays raw
    } else {
        v = (j & 1) ? cosf(angle) : sinf(angle);
    }
    pe[idx] = v;
}

// ---------------------------------------------------------------------------
// Kernel 2: row scatter. For row index idx = b*S + i of either half:
//   node = sol[b][i];  out[half][b][node][:] = pe[i][:]
// 32 lanes per row, each lane moves one float4 (128 floats = 512 B per row).
// ---------------------------------------------------------------------------
__global__ __launch_bounds__(256) void scatter_kernel(
        const int* __restrict__ sol, const int* __restrict__ best,
        const float* __restrict__ pe, float* __restrict__ out) {
    const int ROWS = 2 * BB * SS;
    const int lane = threadIdx.x & 31;   // 32 lanes per row
    const int rib  = threadIdx.x >> 5;   // 8 rows per 256-thread block
    for (int r = blockIdx.x * 8 + rib; r < ROWS; r += gridDim.x * 8) {
        const int half = (r >= BB * SS) ? 1 : 0;
        const int idx  = half ? (r - BB * SS) : r;   // b*S + i
        const int i    = idx & (SS - 1);
        const int node = half ? best[idx] : sol[idx];
        // dst row = half*B*S + b*S + node  = half*B*S + (idx - i) + node
        const int dstRow = half * (BB * SS) + (idx - i) + node;
        const float4* __restrict__ src = (const float4*)(pe + (size_t)i * DD);
        float4* __restrict__ dst = (float4*)(out + (size_t)dstRow * DD);
        dst[lane] = src[lane];
    }
}

// ---------------------------------------------------------------------------
// Fallback (ws too small): compute pe on the fly per output row.
// ---------------------------------------------------------------------------
__global__ __launch_bounds__(256) void scatter_fused_kernel(
        const int* __restrict__ sol, const int* __restrict__ best,
        float* __restrict__ out) {
    const int ROWS = 2 * BB * SS;
    const int lane = threadIdx.x & 31;
    const int rib  = threadIdx.x >> 5;
    for (int r = blockIdx.x * 8 + rib; r < ROWS; r += gridDim.x * 8) {
        const int half = (r >= BB * SS) ? 1 : 0;
        const int idx  = half ? (r - BB * SS) : r;
        const int i    = idx & (SS - 1);
        const int node = half ? best[idx] : sol[idx];
        const int dstRow = half * (BB * SS) + (idx - i) + node;
        float4 v;
        float* vp = (float*)&v;
        #pragma unroll
        for (int q = 0; q < 4; ++q) {
            int j = lane * 4 + q;
            float expo = -(float)(2 * (j >> 1)) / (float)DD;
            float invf = powf(10000.0f, expo);
            float angle = (float)(i + 1) * invf;
            if (i == 0) vp[q] = angle;
            else        vp[q] = (j & 1) ? cosf(angle) : sinf(angle);
        }
        ((float4*)(out + (size_t)dstRow * DD))[lane] = v;
    }
}

extern "C" void kernel_launch(void* const* d_in, const int* in_sizes, int n_in,
                              void* d_out, int out_size, void* d_ws, size_t ws_size,
                              hipStream_t stream) {
    // inputs: d_in[0] = x (f32, unused), d_in[1] = solutions (int), d_in[2] = best_solutions (int)
    const int* sol  = (const int*)d_in[1];
    const int* best = (const int*)d_in[2];
    float* out = (float*)d_out;

    const size_t peBytes = (size_t)SS * DD * sizeof(float);
    const int ROWS = 2 * BB * SS;
    const int SCATTER_BLOCKS = 8192;       // 65536 row-groups / 8192 = 8 iters/block

    if (ws_size >= peBytes) {
        float* pe = (float*)d_ws;
        pe_init_kernel<<<(SS * DD + 255) / 256, 256, 0, stream>>>(pe);
        scatter_kernel<<<SCATTER_BLOCKS, 256, 0, stream>>>(sol, best, pe, out);
    } else {
        scatter_fused_kernel<<<SCATTER_BLOCKS, 256, 0, stream>>>(sol, best, out);
    }
    (void)in_sizes; (void)n_in; (void)out_size; (void)ROWS;
}